// Round 5
// baseline (179.276 us; speedup 1.0000x reference)
//
#include <hip/hip_runtime.h>

// B=32, H=W=128, C_IN=C_OUT=32, 3x3 SAME conv, per-sample hypernet weights
// Wk[b] = (P[b] @ dense_w).reshape(3,3,32,32).
//
// R10: direct-f32 conv, bf-in-LDS, pinned 3-slot load pipeline.
//  R9 post-mortem: VGPR=84 = bf(72)+acc(8)+addr -> pipeline slots got ZERO
//  registers; compiler sank every trio load to its consume (branches around
//  ISSUE + bf reg pressure). 24 full-latency stalls/row reproduces the
//  measured 81us exactly. FIX: (1) bf moved to LDS (18.4KB, lane*16
//  contiguous ds_read_b128 = conflict-free canonical frag pattern) ->
//  pressure ~110, sinking motive gone; (2) ISSUE made branch-free
//  (unconditional loads from clamped row ptrs; invalid-kh handled at consume
//  by SKIPPING the MFMA group); (3) 3-slot / 2-step-lookahead pipeline with
//  __builtin_amdgcn_sched_barrier(0) after each ISSUE -> sinking illegal.
//  16 waves/CU (grid 1024, bounds (256,4), cap 128 VGPR).

#define BATCH 32
#define HDIM 128
#define WDIM 128
#define CIN 32
#define COUT 32
#define PDIM 128
#define KCOLS 9216  // 3*3*32*32

typedef _Float16 f16x8 __attribute__((ext_vector_type(8)));
typedef float f32x4 __attribute__((ext_vector_type(4)));

__device__ __forceinline__ f16x8 zero8() {
    f16x8 z;
#pragma unroll
    for (int j = 0; j < 8; ++j) z[j] = (_Float16)0.f;
    return z;
}

__device__ __forceinline__ f16x8 cvt8(f32x4 lo, f32x4 hi) {
    f16x8 o;
#pragma unroll
    for (int j = 0; j < 4; ++j) {
        o[j] = (_Float16)lo[j];
        o[4 + j] = (_Float16)hi[j];
    }
    return o;
}

// ---------------------------------------------------------------------------
// hyper_gemm: A = P @ dense_w -> f16, swizzled to MFMA B-frag layout
// WB[b][((kc*2 + co>>4)*64 + (ci>>3)*16 + (co&15))*8 + (ci&7)].
// 288 blocks x 256 thr (verified R8/R9). Dw col-panel read twice (L3-served).
// ---------------------------------------------------------------------------
__global__ __launch_bounds__(256) void hyper_gemm(const float* __restrict__ P,
                                                  const float* __restrict__ Dw,
                                                  unsigned short* __restrict__ WB) {
    const int tid = threadIdx.x;
    const int lane = tid & 63;
    const int cg = blockIdx.x % 144;
    const int bq = blockIdx.x / 144;  // 0..1
    const int col = cg * 64 + lane;
    const int b0 = __builtin_amdgcn_readfirstlane(bq * 16 + (tid >> 6) * 4);
    const float* pb = P + (size_t)b0 * PDIM;  // wave-uniform base -> s_load

    float acc[4];
#pragma unroll
    for (int j = 0; j < 4; ++j) acc[j] = 0.f;

#pragma unroll 2
    for (int mm = 0; mm < PDIM; mm += 16) {
        float d[16];
#pragma unroll
        for (int u = 0; u < 16; ++u) d[u] = Dw[(size_t)(mm + u) * KCOLS + col];
#pragma unroll
        for (int u = 0; u < 16; ++u) {
#pragma unroll
            for (int j = 0; j < 4; ++j) acc[j] += d[u] * pb[j * PDIM + mm + u];
        }
    }

    const int co = col & 31;
    const int k = col >> 5;
    const int kc = k >> 5;
    const int ci = k & 31;
    const int base =
        ((kc * 2 + (co >> 4)) * 64 + (ci >> 3) * 16 + (co & 15)) * 8 + (ci & 7);
#pragma unroll
    for (int j = 0; j < 4; ++j) {
        _Float16 v = (_Float16)acc[j];
        WB[(size_t)(b0 + j) * KCOLS + base] = __builtin_bit_cast(unsigned short, v);
    }
}

// ---------------------------------------------------------------------------
// conv_direct: implicit-GEMM conv reading f32 X straight from global.
// Grid 1024 (XCD-swizzled), block = 256 thr / 4 waves, wave = one output row
// (8 tiles of 16 px). Steps n = t*3+kh; 3-slot pipeline (slot = kh), 2-step
// lookahead, sched_barrier(0)-pinned issue. B-frags in LDS (18.4 KB).
// ---------------------------------------------------------------------------

// Load one kw tap (16 px x 8 ci as 2 f32x4) of trio (TT, KH) into slot S.
// rp##KH is the row base (pre-clamped for invalid kh -> safe garbage,
// discarded at consume). TT compile-time; edge clamps only materialize
// at TT==0 / TT==7.
#define LDKW(S, TT, KH, KW)                                   \
    {                                                         \
        int ww = (TT) * 16 + m16 + (KW) - 1;                  \
        if ((TT) == 0 && (KW) == 0) ww = ww < 0 ? 0 : ww;     \
        if ((TT) == 7 && (KW) == 2) ww = ww > 127 ? 127 : ww; \
        const float* p = rp##KH + ww * CIN + qo;              \
        L[S][KW][0] = *(const f32x4*)p;                       \
        L[S][KW][1] = *(const f32x4*)(p + 4);                 \
    }

#define KHVALID(KH) ((KH) == 0 ? v0 : ((KH) == 2 ? v2 : true))

// Branch-free issue (always executes) + pin: loads may not sink below.
#define ISSUE(S, TT, KH)                      \
    {                                         \
        LDKW(S, TT, KH, 0)                    \
        LDKW(S, TT, KH, 1)                    \
        LDKW(S, TT, KH, 2)                    \
        __builtin_amdgcn_sched_barrier(0);    \
    }

// Consume slot S for (TT, KH). Invalid kh (wave-uniform, only image top/
// bottom rows): skip cvt + ds_read + MFMA entirely (A would be zero).
#define CONSUME(S, TT, KH)                                                                             \
    if (KHVALID(KH)) {                                                                                 \
        f16x8 a0 = cvt8(L[S][0][0], L[S][0][1]);                                                       \
        f16x8 a1 = cvt8(L[S][1][0], L[S][1][1]);                                                       \
        f16x8 a2 = cvt8(L[S][2][0], L[S][2][1]);                                                       \
        if ((TT) == 0 && m16 == 0) a0 = zero8();                                                       \
        if ((TT) == 7 && m16 == 15) a2 = zero8();                                                      \
        acc0 = __builtin_amdgcn_mfma_f32_16x16x32_f16(a0, BF[(((KH)*3 + 0) * 2 + 0) * 64 + lane], acc0, 0, 0, 0); \
        acc1 = __builtin_amdgcn_mfma_f32_16x16x32_f16(a0, BF[(((KH)*3 + 0) * 2 + 1) * 64 + lane], acc1, 0, 0, 0); \
        acc0 = __builtin_amdgcn_mfma_f32_16x16x32_f16(a1, BF[(((KH)*3 + 1) * 2 + 0) * 64 + lane], acc0, 0, 0, 0); \
        acc1 = __builtin_amdgcn_mfma_f32_16x16x32_f16(a1, BF[(((KH)*3 + 1) * 2 + 1) * 64 + lane], acc1, 0, 0, 0); \
        acc0 = __builtin_amdgcn_mfma_f32_16x16x32_f16(a2, BF[(((KH)*3 + 2) * 2 + 0) * 64 + lane], acc0, 0, 0, 0); \
        acc1 = __builtin_amdgcn_mfma_f32_16x16x32_f16(a2, BF[(((KH)*3 + 2) * 2 + 1) * 64 + lane], acc1, 0, 0, 0); \
    }

__global__ __launch_bounds__(256, 4) void conv_direct(const float* __restrict__ X,
                                                      const unsigned short* __restrict__ WB,
                                                      float* __restrict__ Y) {
    __shared__ f16x8 BF[KCOLS / 8];  // 18432 B: frag i at [i*64 + lane]
    const int tid = threadIdx.x;

    // XCD-aware swizzle: 1024 % 8 == 0 -> simple bijective form.
    // XCD x owns images 4x..4x+3 entirely (tap reuse + WB L2-local).
    const int wg = blockIdx.x;
    const int id = (wg & 7) * 128 + (wg >> 3);
    const int b = id >> 5;   // image
    const int hg = id & 31;  // 4-row group
    const int wave = tid >> 6;
    const int lane = tid & 63;
    const int q = lane >> 4;    // ci octet
    const int m16 = lane & 15;  // pixel within tile
    const int h = hg * 4 + wave;
    const int qo = q * 8;

    // ---- stage B-frag table to LDS (1152 x 16B, coalesced) ----
    {
        const f16x8* wbp = (const f16x8*)(WB + (size_t)b * KCOLS);
        for (int i = tid; i < KCOLS / 8; i += 256) BF[i] = wbp[i];
    }
    __syncthreads();

    const bool v0 = (h > 0);
    const bool v2 = (h < HDIM - 1);
    const float* xb = X + (size_t)b * HDIM * WDIM * CIN;
    const float* rp0 = xb + (size_t)(v0 ? h - 1 : 0) * WDIM * CIN;
    const float* rp1 = xb + (size_t)h * WDIM * CIN;
    const float* rp2 = xb + (size_t)(v2 ? h + 1 : 0) * WDIM * CIN;

    // 3-slot pipeline, slot = kh (period-3 steps), 2-step lookahead.
    f32x4 L[3][3][2];  // all indices compile-time after full unroll

    float* ybase = Y + (((size_t)b * HDIM + h) * WDIM + q * 4) * COUT + m16;

    // prologue: steps 0 (t0,kh0) and 1 (t0,kh1)
    ISSUE(0, 0, 0);
    ISSUE(1, 0, 1);

#pragma unroll
    for (int t = 0; t < 8; ++t) {
        f32x4 acc0 = {0.f, 0.f, 0.f, 0.f};
        f32x4 acc1 = {0.f, 0.f, 0.f, 0.f};

        // step 3t:   issue (t,2),    consume (t,0)
        ISSUE(2, t, 2);
        CONSUME(0, t, 0);
        // step 3t+1: issue (t+1,0),  consume (t,1)
        if (t < 7) ISSUE(0, (t + 1), 0);
        CONSUME(1, t, 1);
        // step 3t+2: issue (t+1,1),  consume (t,2)
        if (t < 7) ISSUE(1, (t + 1), 1);
        CONSUME(2, t, 2);

        // D layout: col = lane&15 (co), row = q*4 + r (pixel). Plain stores:
        // acc0+acc1 halves of each 128B line merge in L2.
        float* yp = ybase + t * 16 * COUT;
#pragma unroll
        for (int r = 0; r < 4; ++r) {
            yp[r * COUT] = acc0[r];
            yp[r * COUT + 16] = acc1[r];
        }
    }
}

extern "C" void kernel_launch(void* const* d_in, const int* in_sizes, int n_in,
                              void* d_out, int out_size, void* d_ws, size_t ws_size,
                              hipStream_t stream) {
    const float* X = (const float*)d_in[0];   // [32,128,128,32]
    const float* P = (const float*)d_in[1];   // [32,128]
    const float* Dw = (const float*)d_in[2];  // [128,9216]
    float* Y = (float*)d_out;                 // [32,128,128,32]
    (void)ws_size;

    unsigned short* WB = (unsigned short*)d_ws;  // 589824 B

    hipLaunchKernelGGL(hyper_gemm, dim3(288), dim3(256), 0, stream, P, Dw, WB);
    hipLaunchKernelGGL(conv_direct, dim3(1024), dim3(256), 0, stream, X, WB, Y);
}

// Round 6
// 138.804 us; speedup vs baseline: 1.2916x; 1.2916x over previous
//
#include <hip/hip_runtime.h>

// B=32, H=W=128, C_IN=C_OUT=32, 3x3 SAME conv, per-sample hypernet weights
// Wk[b] = (P[b] @ dense_w).reshape(3,3,32,32).
//
// R11 = R8 (best measured conv: 42.4us) + two fixes for the proven
// register-prefetch sinking (R8 VGPR=108 / R9 84 / R10 64 all show
// MachineSinking moving loads to their uses):
//  (1) B-frag table in LDS (18.4KB) instead of 72 VGPR -> pressure motive
//      gone. Reads are base+lane*16 with compile-time offsets (<=2-way
//      bank alias = free).
//  (2) g1 prefetch split per-tile: g0 compute tile t issues g1 row t's
//      2 loads (8-VGPR steps interleaved with MFMA) instead of one
//      64-VGPR block -> tiny per-pair sink gain, natural overlap.
// Everything else byte-identical to R8's verified math.
// Adjudicator: conv VGPR_Count ~95-125 => prefetch held; ~50 => sank.

#define BATCH 32
#define HDIM 128
#define WDIM 128
#define CIN 32
#define COUT 32
#define PDIM 128
#define KCOLS 9216  // 3*3*32*32

typedef _Float16 f16x8 __attribute__((ext_vector_type(8)));
typedef float f32x4 __attribute__((ext_vector_type(4)));

__device__ __forceinline__ f16x8 zero8() {
    f16x8 z;
#pragma unroll
    for (int j = 0; j < 8; ++j) z[j] = (_Float16)0.f;
    return z;
}

__device__ __forceinline__ f16x8 cvt8(f32x4 lo, f32x4 hi) {
    f16x8 o;
#pragma unroll
    for (int j = 0; j < 4; ++j) {
        o[j] = (_Float16)lo[j];
        o[4 + j] = (_Float16)hi[j];
    }
    return o;
}

// ---------------------------------------------------------------------------
// hyper_gemm: A = P @ dense_w -> f16, swizzled to MFMA B-frag layout
// WB[b][((kc*2 + co>>4)*64 + (ci>>3)*16 + (co&15))*8 + (ci&7)].
// 288 blocks x 256 thr (verified R8-R10). Dw col-panel read twice (L3-served).
// ---------------------------------------------------------------------------
__global__ __launch_bounds__(256) void hyper_gemm(const float* __restrict__ P,
                                                  const float* __restrict__ Dw,
                                                  unsigned short* __restrict__ WB) {
    const int tid = threadIdx.x;
    const int lane = tid & 63;
    const int cg = blockIdx.x % 144;
    const int bq = blockIdx.x / 144;  // 0..1
    const int col = cg * 64 + lane;
    const int b0 = __builtin_amdgcn_readfirstlane(bq * 16 + (tid >> 6) * 4);
    const float* pb = P + (size_t)b0 * PDIM;  // wave-uniform base -> s_load

    float acc[4];
#pragma unroll
    for (int j = 0; j < 4; ++j) acc[j] = 0.f;

#pragma unroll 2
    for (int mm = 0; mm < PDIM; mm += 16) {
        float d[16];
#pragma unroll
        for (int u = 0; u < 16; ++u) d[u] = Dw[(size_t)(mm + u) * KCOLS + col];
#pragma unroll
        for (int u = 0; u < 16; ++u) {
#pragma unroll
            for (int j = 0; j < 4; ++j) acc[j] += d[u] * pb[j * PDIM + mm + u];
        }
    }

    const int co = col & 31;
    const int k = col >> 5;
    const int kc = k >> 5;
    const int ci = k & 31;
    const int base =
        ((kc * 2 + (co >> 4)) * 64 + (ci >> 3) * 16 + (co & 15)) * 8 + (ci & 7);
#pragma unroll
    for (int j = 0; j < 4; ++j) {
        _Float16 v = (_Float16)acc[j];
        WB[(size_t)(b0 + j) * KCOLS + base] = __builtin_bit_cast(unsigned short, v);
    }
}

// ---------------------------------------------------------------------------
// conv_fused: implicit-GEMM conv, stream-pipelined, B-frags in LDS.
// Grid 256 (XCD-swizzled), block = 512 thr / 8 waves, owns 16 rows.
// LDS: Xs 128 KB = [16 rows][128 px][4 x 16B slots], slot = q ^ (px>>1);
//      BFs 18.4 KB (frag i at [i*64 + lane]). Total 149.5 KB, 1 block/CU.
// Pipeline: stage g0 -> barrier -> compute g0 (tile t also issues g1 row t's
// 2 global loads) -> cvt+write g1 -> barrier -> compute g1.
// ---------------------------------------------------------------------------
__device__ __forceinline__ f16x8 halo_ld(const f32x4* __restrict__ gp, int px) {
    const bool ok = (unsigned)px < 128u;
    const int p = ok ? px : 0;
    f32x4 lo = gp[p * 8];
    f32x4 hi = gp[p * 8 + 1];
    f16x8 o;
#pragma unroll
    for (int j = 0; j < 4; ++j) {
        o[j] = (_Float16)lo[j];
        o[4 + j] = (_Float16)hi[j];
    }
    if (!ok) o = zero8();
    return o;
}

// One 8-row group. TOPG: wave0 takes kh==0 from global halo (group 0);
// otherwise wave0's (wave-1) addressing falls through into the previous
// group's last LDS row. wave7 always takes kh==2 via the global path.
// PRE: tile t issues the 2 global loads of next-group row t into R.
template <bool TOPG, bool PRE>
__device__ __forceinline__ void compute_group(const char* xsb, int ldsbase,
                                              const f16x8* bfl, float* ybase,
                                              const f32x4* gp, bool gvalid,
                                              int wave, int q, int m16,
                                              f32x4* R, const float* xsrc1) {
    f16x8 hal[3];
    if (gvalid) {
#pragma unroll
        for (int kw = 0; kw < 3; ++kw) hal[kw] = halo_ld(gp, m16 + kw - 1);
    } else {
#pragma unroll
        for (int kw = 0; kw < 3; ++kw) hal[kw] = zero8();
    }

    int va[3];
#pragma unroll
    for (int kw = 0; kw < 3; ++kw) {
        const int px = m16 + kw - 1;
        const int sl = (q ^ (px >> 1)) & 3;
        va[kw] = ldsbase + (wave - 1) * 8192 + px * 64 + sl * 16;
    }

#pragma unroll
    for (int t = 0; t < 8; ++t) {
        if constexpr (PRE) {  // issue next-group row t (2 x dwordx4)
            R[2 * t] = *(const f32x4*)(xsrc1 + (size_t)t * WDIM * CIN);
            R[2 * t + 1] = *(const f32x4*)(xsrc1 + (size_t)t * WDIM * CIN + 4);
        }

        f32x4 acc0 = {0.f, 0.f, 0.f, 0.f};
        f32x4 acc1 = {0.f, 0.f, 0.f, 0.f};

#pragma unroll
        for (int kh = 0; kh < 3; ++kh) {
            f16x8 a0, a1, a2;
            const bool use_lds = (kh == 1) || (kh == 0 && (!TOPG || wave != 0)) ||
                                 (kh == 2 && wave != 7);
            if (use_lds) {
                int v0 = va[0] + kh * 8192;
                int v1 = va[1] + kh * 8192;
                int v2 = va[2] + kh * 8192;
                if (t == 0) v0 += (m16 == 0) ? 64 : 0;   // px=-1 -> safe slot
                if (t == 7) v2 -= (m16 == 15) ? 64 : 0;  // px=128 -> safe slot
                a0 = *(const f16x8*)(xsb + v0);
                a1 = *(const f16x8*)(xsb + v1);
                a2 = *(const f16x8*)(xsb + v2);
                if (t == 0 && m16 == 0) a0 = zero8();
                if (t == 7 && m16 == 15) a2 = zero8();
            } else {
                a0 = hal[0];
                a1 = hal[1];
                a2 = hal[2];
                if (gvalid && t < 7) {  // prefetch next tile's halo trio
#pragma unroll
                    for (int kw = 0; kw < 3; ++kw)
                        hal[kw] = halo_ld(gp, (t + 1) * 16 + m16 + kw - 1);
                }
            }
            acc0 = __builtin_amdgcn_mfma_f32_16x16x32_f16(a0, bfl[((kh * 3 + 0) * 2 + 0) * 64], acc0, 0, 0, 0);
            acc1 = __builtin_amdgcn_mfma_f32_16x16x32_f16(a0, bfl[((kh * 3 + 0) * 2 + 1) * 64], acc1, 0, 0, 0);
            acc0 = __builtin_amdgcn_mfma_f32_16x16x32_f16(a1, bfl[((kh * 3 + 1) * 2 + 0) * 64], acc0, 0, 0, 0);
            acc1 = __builtin_amdgcn_mfma_f32_16x16x32_f16(a1, bfl[((kh * 3 + 1) * 2 + 1) * 64], acc1, 0, 0, 0);
            acc0 = __builtin_amdgcn_mfma_f32_16x16x32_f16(a2, bfl[((kh * 3 + 2) * 2 + 0) * 64], acc0, 0, 0, 0);
            acc1 = __builtin_amdgcn_mfma_f32_16x16x32_f16(a2, bfl[((kh * 3 + 2) * 2 + 1) * 64], acc1, 0, 0, 0);
        }

        // D layout: col = lane&15 (co), row = q*4 + r (pixel). Plain stores:
        // acc0+acc1 halves of each 128B line merge in L2.
        float* yp = ybase + t * 16 * COUT;
#pragma unroll
        for (int r = 0; r < 4; ++r) {
            yp[r * COUT] = acc0[r];
            yp[r * COUT + 16] = acc1[r];
        }

#pragma unroll
        for (int kw = 0; kw < 3; ++kw) va[kw] += 1024;  // +16 px
    }
}

__global__ __launch_bounds__(512, 2) void conv_fused(const float* __restrict__ X,
                                                     const unsigned short* __restrict__ WB,
                                                     float* __restrict__ Y) {
    __shared__ f16x8 Xs[16 * 512];     // 128 KB: [row 0..15][px*4 + slot]
    __shared__ f16x8 BFs[KCOLS / 8];   // 18432 B: frag i at [i*64 + lane]
    const int tid = threadIdx.x;

    // XCD-aware swizzle: 256 % 8 == 0 -> simple bijective form.
    const int wg = blockIdx.x;
    const int id = (wg & 7) * 32 + (wg >> 3);
    const int b = id >> 3;
    const int hg = id & 7;
    const int r0 = hg * 16;

    const int wave = tid >> 6;
    const int lane = tid & 63;
    const int q = lane >> 4;    // ci octet
    const int m16 = lane & 15;  // pixel within tile

    // ---- stage B-frag table to LDS (1152 x 16B, coalesced) ----
    {
        const f16x8* wbp = (const f16x8*)(WB + (size_t)b * KCOLS);
        for (int i = tid; i < KCOLS / 8; i += 512) BFs[i] = wbp[i];
    }

    // ---- staging geometry (thread covers one px octet across rows) ----
    const int px_s = tid >> 2;  // 0..127
    const int q_s = tid & 3;
    const int g_s = px_s * 4 + ((q_s ^ (px_s >> 1)) & 3);
    const float* xsrc = X + (((size_t)b * HDIM + r0) * WDIM + px_s) * CIN + q_s * 8;

    // ---- prologue: stage group-0 rows (0..7) ----
#pragma unroll
    for (int r = 0; r < 8; ++r) {
        f32x4 lo = *(const f32x4*)(xsrc + (size_t)r * WDIM * CIN);
        f32x4 hi = *(const f32x4*)(xsrc + (size_t)r * WDIM * CIN + 4);
        Xs[r * 512 + g_s] = cvt8(lo, hi);
    }

    __syncthreads();

    const char* xsb = (const char*)Xs;
    const f16x8* bfl = BFs + lane;
    const f32x4* Xb = (const f32x4*)X + (size_t)b * HDIM * (WDIM * CIN / 4);
    const float* xsrc1 = xsrc + (size_t)8 * WDIM * CIN;  // g1 rows 8..15
    f32x4 R[16];

    // ---- group 0: rows r0..r0+7 (tile t issues g1 row t's loads) ----
    {
        const bool gvalid = (wave == 0) ? (hg != 0) : (wave == 7);
        const int grow = (wave == 0) ? (hg ? r0 - 1 : 0) : (r0 + 8);
        const f32x4* gp = Xb + (size_t)grow * (WDIM * CIN / 4) + q * 2;
        float* yb = Y + (((size_t)b * HDIM + r0 + wave) * WDIM + q * 4) * COUT + m16;
        compute_group<true, true>(xsb, 0, bfl, yb, gp, gvalid, wave, q, m16, R, xsrc1);
    }

    // ---- write group-1 rows (disjoint LDS region from group-0 reads) ----
#pragma unroll
    for (int r = 0; r < 8; ++r) {
        Xs[(8 + r) * 512 + g_s] = cvt8(R[2 * r], R[2 * r + 1]);
    }
    __syncthreads();

    // ---- group 1: rows r0+8..r0+15 (top halo = LDS row 7, falls through) ----
    {
        const bool gvalid = (wave == 7) && (hg != 7);
        const int grow = gvalid ? (r0 + 16) : 0;
        const f32x4* gp = Xb + (size_t)grow * (WDIM * CIN / 4) + q * 2;
        float* yb = Y + (((size_t)b * HDIM + r0 + 8 + wave) * WDIM + q * 4) * COUT + m16;
        compute_group<false, false>(xsb, 8 * 8192, bfl, yb, gp, gvalid, wave, q, m16,
                                    R, xsrc1);
    }
}

extern "C" void kernel_launch(void* const* d_in, const int* in_sizes, int n_in,
                              void* d_out, int out_size, void* d_ws, size_t ws_size,
                              hipStream_t stream) {
    const float* X = (const float*)d_in[0];   // [32,128,128,32]
    const float* P = (const float*)d_in[1];   // [32,128]
    const float* Dw = (const float*)d_in[2];  // [128,9216]
    float* Y = (float*)d_out;                 // [32,128,128,32]
    (void)ws_size;

    unsigned short* WB = (unsigned short*)d_ws;  // 589824 B

    hipLaunchKernelGGL(hyper_gemm, dim3(288), dim3(256), 0, stream, P, Dw, WB);
    hipLaunchKernelGGL(conv_fused, dim3(256), dim3(512), 0, stream, X, WB, Y);
}